// Round 6
// baseline (1754.171 us; speedup 1.0000x reference)
//
#include <hip/hip_runtime.h>
#include <hip/hip_bf16.h>
#include <math.h>

#define S 2048
#define HID 1024
#define NH 8
#define HD 128
#define INTER 4096
#define EPSV 1e-6f
#define THETA 10000.0f

typedef __hip_bfloat16 bf16;
typedef unsigned short u16;
typedef __attribute__((ext_vector_type(8))) short bf16x8;  // 8 bf16 = 4 VGPRs
typedef __attribute__((ext_vector_type(4))) float f32x4;

__device__ inline float bu2f(u16 u) {
    unsigned int x = ((unsigned int)u) << 16;
    return __uint_as_float(x);
}
__device__ inline u16 f2bu(float f) {
    bf16 h = __float2bfloat16(f);
    return *reinterpret_cast<u16*>(&h);
}
__device__ inline float ldin(const void* p, size_t i, bool isbf) {
    return isbf ? bu2f(((const u16*)p)[i]) : ((const float*)p)[i];
}
__device__ inline float gelu_tanh(float x) {
    float x3 = x * x * x;
    return 0.5f * x * (1.f + tanhf(0.7978845608028654f * (x + 0.044715f * x3)));
}

// ---------------- dtype probe (round-1 notes) ----------------
__global__ __launch_bounds__(256) void probe_kernel(const unsigned short* __restrict__ x,
                                                    int* __restrict__ flag) {
    __shared__ int red[256];
    int tid = threadIdx.x;
    int cnt = 0;
    for (int i = tid; i < 2048; i += 256) {
        unsigned short u = x[2 * i];
        int e = (u >> 7) & 0xFF;
        cnt += (e >= 110 && e <= 135) ? 1 : 0;
    }
    red[tid] = cnt;
    __syncthreads();
    for (int off = 128; off > 0; off >>= 1) {
        if (tid < off) red[tid] += red[tid + off];
        __syncthreads();
    }
    if (tid == 0) *flag = (red[0] > 1024) ? 1 : 0;
}

// ------- batched weight transpose: z picks source; dest = WT + z*K*N (NxK bf16) -------
__global__ __launch_bounds__(256) void transpose_w4(const void* __restrict__ W0,
                                                    const void* __restrict__ W1,
                                                    const void* __restrict__ W2,
                                                    const void* __restrict__ W3,
                                                    u16* __restrict__ WT,
                                                    const int* __restrict__ flag,
                                                    int K, int N) {
    bool isbf = (*flag != 0);
    const void* Ws[4] = {W0, W1, W2, W3};
    const void* W = Ws[blockIdx.z];
    u16* dst = WT + (size_t)blockIdx.z * ((size_t)K * N);
    __shared__ float t[32][33];
    int n0 = blockIdx.x * 32, k0 = blockIdx.y * 32;
    int c = threadIdx.x & 31, r = threadIdx.x >> 5;
#pragma unroll
    for (int p = 0; p < 4; p++)
        t[r + 8 * p][c] = ldin(W, (size_t)(k0 + r + 8 * p) * N + n0 + c, isbf);
    __syncthreads();
#pragma unroll
    for (int p = 0; p < 4; p++) {
        int row = r + 8 * p;
        dst[(size_t)(n0 + row) * K + k0 + c] = f2bu(t[c][row]);
    }
}

// ---------------- V transpose: V[key][dh] (stride sv) -> VT[dh][key] ----------------
__global__ __launch_bounds__(256) void transpose_v(const u16* __restrict__ V, int sv,
                                                   u16* __restrict__ VT) {
    __shared__ u16 t[32][33];
    int k0 = blockIdx.x * 32;
    int d0 = blockIdx.y * 32;
    int c = threadIdx.x & 31, r = threadIdx.x >> 5;
#pragma unroll
    for (int p = 0; p < 4; p++)
        t[r + 8 * p][c] = V[(size_t)(k0 + r + 8 * p) * sv + d0 + c];
    __syncthreads();
#pragma unroll
    for (int p = 0; p < 4; p++)
        VT[(size_t)(d0 + r + 8 * p) * S + k0 + c] = t[c][r + 8 * p];
}

// ---------------- RMSNorm -> bf16 ----------------
__global__ __launch_bounds__(256) void rmsnorm_kernel(const void* __restrict__ x,
                                                      const void* __restrict__ w,
                                                      u16* __restrict__ y,
                                                      const int* __restrict__ flag,
                                                      int dual) {
    bool isbf = (*flag != 0);
    bool xbf = dual && isbf;
    int row = blockIdx.x;
    size_t base = (size_t)row * HID;
    __shared__ float red[256];
    float xv[4];
    float s = 0.f;
#pragma unroll
    for (int i = 0; i < 4; i++) {
        float v = ldin(x, base + threadIdx.x + 256 * i, xbf);
        xv[i] = v;
        s += v * v;
    }
    red[threadIdx.x] = s;
    __syncthreads();
    for (int off = 128; off > 0; off >>= 1) {
        if (threadIdx.x < off) red[threadIdx.x] += red[threadIdx.x + off];
        __syncthreads();
    }
    float scale = rsqrtf(red[0] / (float)HID + EPSV);
#pragma unroll
    for (int i = 0; i < 4; i++) {
        int c = threadIdx.x + 256 * i;
        y[base + c] = f2bu(xv[i] * scale * (1.f + ldin(w, c, isbf)));
    }
}

// ================= MFMA GEMM, double-buffered LDS + VGPR prefetch =================
// C(MxN) = A(MxK bf16) @ B; BT = B^T (NxK bf16). One __syncthreads per K-step:
// store-regs -> sync -> issue next-tile global loads -> MFMA on current buffer.
template <int BM, int BN, int WRN, int WCN, int EPI>
__global__ __launch_bounds__(256) void gemm_mfma(const u16* __restrict__ A,
                                                 const u16* __restrict__ BT,
                                                 float* __restrict__ Cf,
                                                 u16* __restrict__ Cb,
                                                 const void* __restrict__ res,
                                                 const int* __restrict__ flag,
                                                 int M, int N, int K) {
    constexpr int BK = 32, LDK = 40;
    constexpr int WM = BM / WRN, WN = BN / WCN, TI = WM / 16, TJ = WN / 16;
    constexpr int AIT = BM / 64, BIT = BN / 64;
    __shared__ u16 As[2][BM * LDK];
    __shared__ u16 Bs[2][BN * LDK];
    int tid = threadIdx.x, lane = tid & 63, wv = tid >> 6;
    int wr = wv / WCN, wc = wv % WCN;
    int m = lane & 15, quad = lane >> 4;
    int m0 = blockIdx.y * BM, n0 = blockIdx.x * BN;

    uint4 ra[AIT], rb[BIT];
#pragma unroll
    for (int i = 0; i < AIT; i++) {
        int l = tid + 256 * i, row = l >> 2, kq = l & 3;
        ra[i] = *reinterpret_cast<const uint4*>(&A[(size_t)(m0 + row) * K + kq * 8]);
    }
#pragma unroll
    for (int i = 0; i < BIT; i++) {
        int l = tid + 256 * i, row = l >> 2, kq = l & 3;
        rb[i] = *reinterpret_cast<const uint4*>(&BT[(size_t)(n0 + row) * K + kq * 8]);
    }

    f32x4 acc[TI][TJ] = {};
    const int nk = K / BK;
    for (int t = 0; t < nk; t++) {
        u16* Ab = As[t & 1];
        u16* Bb = Bs[t & 1];
#pragma unroll
        for (int i = 0; i < AIT; i++) {
            int l = tid + 256 * i, row = l >> 2, kq = l & 3;
            *reinterpret_cast<uint4*>(&Ab[row * LDK + kq * 8]) = ra[i];
        }
#pragma unroll
        for (int i = 0; i < BIT; i++) {
            int l = tid + 256 * i, row = l >> 2, kq = l & 3;
            *reinterpret_cast<uint4*>(&Bb[row * LDK + kq * 8]) = rb[i];
        }
        __syncthreads();
        if (t + 1 < nk) {
            int k0 = (t + 1) * BK;
#pragma unroll
            for (int i = 0; i < AIT; i++) {
                int l = tid + 256 * i, row = l >> 2, kq = l & 3;
                ra[i] = *reinterpret_cast<const uint4*>(&A[(size_t)(m0 + row) * K + k0 + kq * 8]);
            }
#pragma unroll
            for (int i = 0; i < BIT; i++) {
                int l = tid + 256 * i, row = l >> 2, kq = l & 3;
                rb[i] = *reinterpret_cast<const uint4*>(&BT[(size_t)(n0 + row) * K + k0 + kq * 8]);
            }
        }
        bf16x8 af[TI], bf_[TJ];
#pragma unroll
        for (int i = 0; i < TI; i++)
            af[i] = *reinterpret_cast<const bf16x8*>(&Ab[(wr * WM + i * 16 + m) * LDK + quad * 8]);
#pragma unroll
        for (int j = 0; j < TJ; j++)
            bf_[j] = *reinterpret_cast<const bf16x8*>(&Bb[(wc * WN + j * 16 + m) * LDK + quad * 8]);
#pragma unroll
        for (int i = 0; i < TI; i++)
#pragma unroll
            for (int j = 0; j < TJ; j++)
                acc[i][j] = __builtin_amdgcn_mfma_f32_16x16x32_bf16(af[i], bf_[j], acc[i][j], 0, 0, 0);
    }
    bool isbf = (EPI == 1) ? (*flag != 0) : false;
#pragma unroll
    for (int i = 0; i < TI; i++) {
#pragma unroll
        for (int j = 0; j < TJ; j++) {
#pragma unroll
            for (int r = 0; r < 4; r++) {
                int row = m0 + wr * WM + i * 16 + quad * 4 + r;
                int col = n0 + wc * WN + j * 16 + m;
                size_t idx = (size_t)row * N + col;
                float v = acc[i][j][r];
                if (EPI == 0) Cb[idx] = f2bu(v);
                else if (EPI == 1) Cf[idx] = v + ldin(res, idx, isbf);
                else Cf[idx] = Cf[idx] + v;
            }
        }
    }
}

// ------------- Fused gated MLP MFMA (dbuf): C(bf16) = gelu(A@Wg) * (A@Wu) -------------
template <int BM, int BN, int WRN, int WCN>
__global__ __launch_bounds__(256) void gemm_gated_mfma(const u16* __restrict__ A,
                                                       const u16* __restrict__ BgT,
                                                       const u16* __restrict__ BuT,
                                                       u16* __restrict__ C,
                                                       int M, int N, int K) {
    constexpr int BK = 32, LDK = 40;
    constexpr int WM = BM / WRN, WN = BN / WCN, TI = WM / 16, TJ = WN / 16;
    constexpr int AIT = BM / 64, BIT = BN / 64;
    __shared__ u16 As[2][BM * LDK];
    __shared__ u16 Bgs[2][BN * LDK];
    __shared__ u16 Bus[2][BN * LDK];
    int tid = threadIdx.x, lane = tid & 63, wv = tid >> 6;
    int wr = wv / WCN, wc = wv % WCN;
    int m = lane & 15, quad = lane >> 4;
    int m0 = blockIdx.y * BM, n0 = blockIdx.x * BN;

    uint4 ra[AIT], rg[BIT], ru[BIT];
#pragma unroll
    for (int i = 0; i < AIT; i++) {
        int l = tid + 256 * i, row = l >> 2, kq = l & 3;
        ra[i] = *reinterpret_cast<const uint4*>(&A[(size_t)(m0 + row) * K + kq * 8]);
    }
#pragma unroll
    for (int i = 0; i < BIT; i++) {
        int l = tid + 256 * i, row = l >> 2, kq = l & 3;
        rg[i] = *reinterpret_cast<const uint4*>(&BgT[(size_t)(n0 + row) * K + kq * 8]);
        ru[i] = *reinterpret_cast<const uint4*>(&BuT[(size_t)(n0 + row) * K + kq * 8]);
    }

    f32x4 accg[TI][TJ] = {};
    f32x4 accu[TI][TJ] = {};
    const int nk = K / BK;
    for (int t = 0; t < nk; t++) {
        u16* Ab = As[t & 1];
        u16* Gb = Bgs[t & 1];
        u16* Ub = Bus[t & 1];
#pragma unroll
        for (int i = 0; i < AIT; i++) {
            int l = tid + 256 * i, row = l >> 2, kq = l & 3;
            *reinterpret_cast<uint4*>(&Ab[row * LDK + kq * 8]) = ra[i];
        }
#pragma unroll
        for (int i = 0; i < BIT; i++) {
            int l = tid + 256 * i, row = l >> 2, kq = l & 3;
            *reinterpret_cast<uint4*>(&Gb[row * LDK + kq * 8]) = rg[i];
            *reinterpret_cast<uint4*>(&Ub[row * LDK + kq * 8]) = ru[i];
        }
        __syncthreads();
        if (t + 1 < nk) {
            int k0 = (t + 1) * BK;
#pragma unroll
            for (int i = 0; i < AIT; i++) {
                int l = tid + 256 * i, row = l >> 2, kq = l & 3;
                ra[i] = *reinterpret_cast<const uint4*>(&A[(size_t)(m0 + row) * K + k0 + kq * 8]);
            }
#pragma unroll
            for (int i = 0; i < BIT; i++) {
                int l = tid + 256 * i, row = l >> 2, kq = l & 3;
                rg[i] = *reinterpret_cast<const uint4*>(&BgT[(size_t)(n0 + row) * K + k0 + kq * 8]);
                ru[i] = *reinterpret_cast<const uint4*>(&BuT[(size_t)(n0 + row) * K + k0 + kq * 8]);
            }
        }
        bf16x8 af[TI], bg[TJ], bu[TJ];
#pragma unroll
        for (int i = 0; i < TI; i++)
            af[i] = *reinterpret_cast<const bf16x8*>(&Ab[(wr * WM + i * 16 + m) * LDK + quad * 8]);
#pragma unroll
        for (int j = 0; j < TJ; j++) {
            bg[j] = *reinterpret_cast<const bf16x8*>(&Gb[(wc * WN + j * 16 + m) * LDK + quad * 8]);
            bu[j] = *reinterpret_cast<const bf16x8*>(&Ub[(wc * WN + j * 16 + m) * LDK + quad * 8]);
        }
#pragma unroll
        for (int i = 0; i < TI; i++)
#pragma unroll
            for (int j = 0; j < TJ; j++) {
                accg[i][j] = __builtin_amdgcn_mfma_f32_16x16x32_bf16(af[i], bg[j], accg[i][j], 0, 0, 0);
                accu[i][j] = __builtin_amdgcn_mfma_f32_16x16x32_bf16(af[i], bu[j], accu[i][j], 0, 0, 0);
            }
    }
#pragma unroll
    for (int i = 0; i < TI; i++)
#pragma unroll
        for (int j = 0; j < TJ; j++)
#pragma unroll
            for (int r = 0; r < 4; r++) {
                int row = m0 + wr * WM + i * 16 + quad * 4 + r;
                int col = n0 + wc * WN + j * 16 + m;
                C[(size_t)row * N + col] = f2bu(gelu_tanh(accg[i][j][r]) * accu[i][j][r]);
            }
}

// ---------------- RoPE: read qkv (stride 3072), write qr/kr (stride 1024) ----------------
__global__ __launch_bounds__(64) void rope_kernel(const u16* __restrict__ qkv,
                                                  u16* __restrict__ qr,
                                                  u16* __restrict__ kr) {
    int b = blockIdx.x;
    int t = b >> 3, h = b & 7;
    int i = threadIdx.x;  // 0..63
    size_t ib = (size_t)t * 3072 + h * HD;
    size_t ob = (size_t)t * HID + h * HD;
    float inv = powf(THETA, -(float)(2 * i) / (float)HD);
    float f = (float)t * inv;
    float c = cosf(f), s = sinf(f);
    float q1 = bu2f(qkv[ib + i]), q2 = bu2f(qkv[ib + i + 64]);
    qr[ob + i] = f2bu(q1 * c - q2 * s);
    qr[ob + i + 64] = f2bu(q2 * c + q1 * s);
    float k1 = bu2f(qkv[ib + 1024 + i]), k2 = bu2f(qkv[ib + 1024 + i + 64]);
    kr[ob + i] = f2bu(k1 * c - k2 * s);
    kr[ob + i + 64] = f2bu(k2 * c + k1 * s);
}

// ============ MFMA flash attention, BQ=128 ============
// Block: 128 queries x 1 head; 4 waves; wave w owns q-rows {16w..16w+15} and
// {64+16w..}. 64-key tiles. Each Ks/VTs b128 read now feeds 2 MFMAs (both
// q-subtiles) -> halves LDS traffic per FLOP vs round 5. Ks re-laid key-major
// [64][136] to kill the 4-way staging-write conflict (t-stride was %32==0).
template <bool CAUSAL>
__global__ __launch_bounds__(256) void attn_mfma_kernel(
    const u16* __restrict__ qa, const u16* __restrict__ qb, int sq,
    const u16* __restrict__ ka, const u16* __restrict__ kb, int sk,
    const u16* __restrict__ vta, const u16* __restrict__ vtb,
    u16* __restrict__ Out, int nkeys) {
    __shared__ u16 Ks[64][136];      // [key][d], 128 d + 8 pad
    __shared__ u16 VTs[2][128][40];  // [key-half][d][key-in-32]
    __shared__ u16 Ps[128][72];      // [q][key]

    int tid = threadIdx.x, lane = tid & 63, w = tid >> 6;
    int col = lane & 15, quad = lane >> 4;
    int q0 = blockIdx.x * 128;
    int h = blockIdx.y;
    const float scale = 0.08838834764831845f;  // 1/sqrt(128)

    int q0r = CAUSAL ? q0 : (q0 & (S - 1));
    const u16* qp = ((CAUSAL || q0 < S) ? qa : qb) + (size_t)q0r * sq + (size_t)h * HD;
    bf16x8 aq[2][4];
#pragma unroll
    for (int qi = 0; qi < 2; qi++)
#pragma unroll
        for (int t = 0; t < 4; t++)
            aq[qi][t] = *reinterpret_cast<const bf16x8*>(
                qp + (size_t)(64 * qi + 16 * w + col) * sq + 32 * t + quad * 8);

    f32x4 o[2][8] = {};
    float m_[2][4], l_[2][4];
#pragma unroll
    for (int qi = 0; qi < 2; qi++)
#pragma unroll
        for (int r = 0; r < 4; r++) {
            m_[qi][r] = -1e30f;
            l_[qi][r] = 0.f;
        }

    int ntiles = CAUSAL ? (q0 >> 6) + 2 : (nkeys >> 6);
    for (int tt = 0; tt < ntiles; tt++) {
        int j0 = tt * 64, j0r = j0 & (S - 1);
        bool eb = (!CAUSAL) && (j0 >= S);
        const u16* kp = eb ? kb : ka;
        const u16* vp = eb ? vtb : vta;
        __syncthreads();
        // ---- stage K tile (key-major) ----
#pragma unroll
        for (int i = 0; i < 4; i++) {
            int l = tid + 256 * i;
            int key = l >> 4, c = l & 15;
            *reinterpret_cast<uint4*>(&Ks[key][c * 8]) =
                *reinterpret_cast<const uint4*>(kp + (size_t)(j0r + key) * sk + h * HD + c * 8);
        }
        // ---- stage V^T tile ----
#pragma unroll
        for (int i = 0; i < 4; i++) {
            int l = tid + 256 * i;
            int d = l >> 3, c = l & 7;
            int ks = c >> 2, kq = c & 3;
            *reinterpret_cast<uint4*>(&VTs[ks][d][kq * 8]) =
                *reinterpret_cast<const uint4*>(vp + (size_t)(h * HD + d) * S + j0r + c * 8);
        }
        __syncthreads();

        bool act0 = !(CAUSAL && j0 > q0);
        bool act1 = !(CAUSAL && j0 > q0 + 64);

        // ---- QK^T: shared Ks read feeds both q-subtiles ----
        f32x4 sc[2][4] = {};
#pragma unroll
        for (int t = 0; t < 4; t++)
#pragma unroll
            for (int ct = 0; ct < 4; ct++) {
                bf16x8 kb_ = *reinterpret_cast<const bf16x8*>(&Ks[16 * ct + col][t * 32 + quad * 8]);
                if (act0) sc[0][ct] = __builtin_amdgcn_mfma_f32_16x16x32_bf16(aq[0][t], kb_, sc[0][ct], 0, 0, 0);
                if (act1) sc[1][ct] = __builtin_amdgcn_mfma_f32_16x16x32_bf16(aq[1][t], kb_, sc[1][ct], 0, 0, 0);
            }

        // ---- online softmax per q-subtile ----
        float alpha[2][4];
#pragma unroll
        for (int qi = 0; qi < 2; qi++) {
            bool act = qi ? act1 : act0;
            if (!act) continue;
            bool diag = CAUSAL && (j0 == q0 + 64 * qi);
#pragma unroll
            for (int ct = 0; ct < 4; ct++)
#pragma unroll
                for (int r = 0; r < 4; r++) {
                    float v = sc[qi][ct][r] * scale;
                    if (diag && (16 * ct + col > 16 * w + 4 * quad + r)) v = -1e30f;
                    sc[qi][ct][r] = v;
                }
#pragma unroll
            for (int r = 0; r < 4; r++) {
                float rmax = fmaxf(fmaxf(sc[qi][0][r], sc[qi][1][r]),
                                   fmaxf(sc[qi][2][r], sc[qi][3][r]));
#pragma unroll
                for (int mk = 1; mk < 16; mk <<= 1) rmax = fmaxf(rmax, __shfl_xor(rmax, mk));
                float mn = fmaxf(m_[qi][r], rmax);
                float al = __expf(m_[qi][r] - mn);
                float p0 = __expf(sc[qi][0][r] - mn);
                float p1 = __expf(sc[qi][1][r] - mn);
                float p2 = __expf(sc[qi][2][r] - mn);
                float p3 = __expf(sc[qi][3][r] - mn);
                float rs = (p0 + p1) + (p2 + p3);
#pragma unroll
                for (int mk = 1; mk < 16; mk <<= 1) rs += __shfl_xor(rs, mk);
                l_[qi][r] = l_[qi][r] * al + rs;
                m_[qi][r] = mn;
                alpha[qi][r] = al;
                int prow = 64 * qi + 16 * w + 4 * quad + r;
                Ps[prow][col] = f2bu(p0);
                Ps[prow][16 + col] = f2bu(p1);
                Ps[prow][32 + col] = f2bu(p2);
                Ps[prow][48 + col] = f2bu(p3);
            }
        }
        // (Ps rows are wave-local; compiler inserts lgkmcnt before reads)

        // ---- PV: O = diag(alpha)*O + P@V, shared VTs read feeds both subtiles ----
#pragma unroll
        for (int qi = 0; qi < 2; qi++) {
            bool act = qi ? act1 : act0;
            if (!act) continue;
#pragma unroll
            for (int nt = 0; nt < 8; nt++)
#pragma unroll
                for (int r = 0; r < 4; r++) o[qi][nt][r] *= alpha[qi][r];
        }
#pragma unroll
        for (int ks = 0; ks < 2; ks++) {
            bf16x8 pa0 = *reinterpret_cast<const bf16x8*>(&Ps[16 * w + col][32 * ks + quad * 8]);
            bf16x8 pa1 = *reinterpret_cast<const bf16x8*>(&Ps[64 + 16 * w + col][32 * ks + quad * 8]);
#pragma unroll
            for (int nt = 0; nt < 8; nt++) {
                bf16x8 vb_ = *reinterpret_cast<const bf16x8*>(&VTs[ks][16 * nt + col][quad * 8]);
                if (act0) o[0][nt] = __builtin_amdgcn_mfma_f32_16x16x32_bf16(pa0, vb_, o[0][nt], 0, 0, 0);
                if (act1) o[1][nt] = __builtin_amdgcn_mfma_f32_16x16x32_bf16(pa1, vb_, o[1][nt], 0, 0, 0);
            }
        }
    }

    // ---- epilogue: O /= l, write bf16 (stride HID) ----
#pragma unroll
    for (int qi = 0; qi < 2; qi++)
#pragma unroll
        for (int r = 0; r < 4; r++) {
            float inv = 1.f / l_[qi][r];
            size_t rowoff =
                (size_t)(q0 + 64 * qi + 16 * w + 4 * quad + r) * HID + (size_t)h * HD;
#pragma unroll
            for (int nt = 0; nt < 8; nt++)
                Out[rowoff + 16 * nt + col] = f2bu(o[qi][nt][r] * inv);
        }
}

// ---------------- f32 -> output dtype (per flag) ----------------
__global__ __launch_bounds__(256) void store_out_kernel(const float* __restrict__ a,
                                                        const float* __restrict__ b,
                                                        void* __restrict__ out,
                                                        const int* __restrict__ flag) {
    bool isbf = (*flag != 0);
    size_t i = (size_t)blockIdx.x * 256 + threadIdx.x;
    const size_t MM = (size_t)S * HID;
    float v = (i < MM) ? a[i] : b[i - MM];
    if (isbf)
        ((bf16*)out)[i] = __float2bfloat16(v);
    else
        ((float*)out)[i] = v;
}

extern "C" void kernel_launch(void* const* d_in, const int* in_sizes, int n_in,
                              void* d_out, int out_size, void* d_ws, size_t ws_size,
                              hipStream_t stream) {
    const void* x[2] = {d_in[0], d_in[1]};
    const void* w_ln[2] = {d_in[5], d_in[14]};
    const void* w_q[2] = {d_in[6], d_in[15]};
    const void* w_k[2] = {d_in[7], d_in[16]};
    const void* w_v[2] = {d_in[8], d_in[17]};
    const void* w_o[2] = {d_in[9], d_in[18]};
    const void* w_pln[2] = {d_in[10], d_in[19]};
    const void* w_g[2] = {d_in[11], d_in[20]};
    const void* w_u[2] = {d_in[12], d_in[21]};
    const void* w_d[2] = {d_in[13], d_in[22]};

    char* base = (char*)d_ws;
    int* flag = (int*)base;
    u16* p = (u16*)(base + 256);
    const size_t E_QKV = (size_t)S * 3072;
    const size_t E_SH = (size_t)S * HID;
    const size_t E_GT = (size_t)S * INTER;
    const size_t E_VT = (size_t)NH * HD * S;
    const size_t MW = (size_t)1024 * 1024;

    u16* qkv[2] = {p, p + E_QKV};            p += 2 * E_QKV;
    u16* qr = p;                             p += E_SH;
    u16* kr = p;                             p += E_SH;
    u16* h_bf = p;                           p += E_SH;
    u16* attnbuf = p;                        p += E_SH;
    u16* vtg[2] = {p, p + E_VT};             p += 2 * E_VT;
    u16* gated = p;                          p += E_GT;  // mixed overlays gated
    u16* mixed = gated;
    u16* wsqT[2] = {p, p + 4 * MW};          p += 8 * MW;  // [wq^T|wk^T|wv^T|wo^T] per expert
    u16* wgT = p;                            p += (size_t)INTER * 1024;  // [wg^T|wu^T] adjacent
    u16* wuT = p;                            p += (size_t)INTER * 1024;
    u16* wdT = p;                            p += (size_t)1024 * INTER;
    float* fbase = (float*)(((size_t)p + 255) & ~(size_t)255);
    float* outX[2] = {fbase, fbase + E_SH};

    probe_kernel<<<1, 256, 0, stream>>>((const unsigned short*)d_in[0], flag);

    for (int e = 0; e < 2; e++) {
        transpose_w4<<<dim3(1024 / 32, 1024 / 32, 4), 256, 0, stream>>>(
            w_q[e], w_k[e], w_v[e], w_o[e], wsqT[e], flag, 1024, 1024);
        transpose_w4<<<dim3(INTER / 32, 1024 / 32, 2), 256, 0, stream>>>(
            w_g[e], w_u[e], w_u[e], w_u[e], wgT, flag, 1024, INTER);
        transpose_w4<<<dim3(1024 / 32, INTER / 32, 1), 256, 0, stream>>>(
            w_d[e], w_d[e], w_d[e], w_d[e], wdT, flag, INTER, 1024);

        rmsnorm_kernel<<<S, 256, 0, stream>>>(x[e], w_ln[e], h_bf, flag, 1);
        gemm_mfma<128, 128, 2, 2, 0><<<dim3(3072 / 128, S / 128), 256, 0, stream>>>(
            h_bf, wsqT[e], nullptr, qkv[e], nullptr, flag, S, 3072, 1024);
        rope_kernel<<<S * NH, 64, 0, stream>>>(qkv[e], qr, kr);
        transpose_v<<<dim3(S / 32, 1024 / 32), 256, 0, stream>>>(qkv[e] + 2048, 3072, vtg[e]);
        attn_mfma_kernel<true><<<dim3(S / 128, NH), 256, 0, stream>>>(
            qr, qr, HID, kr, kr, HID, vtg[e], vtg[e], attnbuf, S);
        gemm_mfma<64, 128, 1, 4, 1><<<dim3(1024 / 128, S / 64), 256, 0, stream>>>(
            attnbuf, wsqT[e] + 3 * MW, outX[e], nullptr, x[e], flag, S, 1024, 1024);
        rmsnorm_kernel<<<S, 256, 0, stream>>>(outX[e], w_pln[e], h_bf, flag, 0);
        gemm_gated_mfma<128, 64, 2, 2><<<dim3(INTER / 64, S / 128), 256, 0, stream>>>(
            h_bf, wgT, wuT, gated, S, INTER, 1024);
        gemm_mfma<64, 128, 1, 4, 2><<<dim3(1024 / 128, S / 64), 256, 0, stream>>>(
            gated, wdT, outX[e], nullptr, nullptr, flag, S, 1024, INTER);
    }

    attn_mfma_kernel<false><<<dim3(2 * S / 128, NH), 256, 0, stream>>>(
        qkv[0], qkv[1], 3072, qkv[0] + 1024, qkv[1] + 1024, 3072,
        vtg[0], vtg[1], mixed, 2 * S);
    gemm_mfma<64, 128, 1, 4, 2><<<dim3(1024 / 128, S / 64), 256, 0, stream>>>(
        mixed, wsqT[0] + 3 * MW, outX[0], nullptr, nullptr, flag, S, 1024, 1024);
    gemm_mfma<64, 128, 1, 4, 2><<<dim3(1024 / 128, S / 64), 256, 0, stream>>>(
        mixed + E_SH, wsqT[1] + 3 * MW, outX[1], nullptr, nullptr, flag, S, 1024, 1024);

    store_out_kernel<<<(2 * E_SH) / 256, 256, 0, stream>>>(outX[0], outX[1], d_out, flag);
}